// Round 1
// baseline (25.909 us; speedup 1.0000x reference)
//
#include <hip/hip_runtime.h>

// SpectralLoss: mean over all 8x8 blocks of (T (x-y) T^T)^2 * W
// B=16, C=3, H=512, W=512  -> 48 images, 64x64 blocks/image, 196608 blocks total.

#define WG 256
#define NWG 768                    // 768*256 == 196608 blocks, one thread each
#define INV_N (1.0f/12582912.0f)   // 16*3*512*512

__global__ __launch_bounds__(WG) void spectral_partial(
    const float* __restrict__ x,
    const float* __restrict__ y,
    const float* __restrict__ Tm,
    const float* __restrict__ Wm,
    float* __restrict__ ws)
{
    const int tid = threadIdx.x;
    const int p   = blockIdx.x * WG + tid;   // global block id
    const int img = p >> 12;                 // /4096 blocks per image
    const int rem = p & 4095;
    const int hb  = rem >> 6;                // block row (64 per image)
    const int wb  = rem & 63;                // block col; consecutive lanes -> adjacent cols
    const int base = img * 262144 + hb * 4096 + wb * 8;

    // 8x8 DCT matrix in registers; uniform address -> compiler scalarizes to SGPRs
    float tT[8][8];
#pragma unroll
    for (int i = 0; i < 8; ++i) {
        float4 t0 = reinterpret_cast<const float4*>(Tm)[2*i];
        float4 t1 = reinterpret_cast<const float4*>(Tm)[2*i+1];
        tT[i][0]=t0.x; tT[i][1]=t0.y; tT[i][2]=t0.z; tT[i][3]=t0.w;
        tT[i][4]=t1.x; tT[i][5]=t1.y; tT[i][6]=t1.z; tT[i][7]=t1.w;
    }

    // M = D * T^T, accumulated row-by-row as diff rows stream in.
    // M[r][l] = sum_j D[r][j] * T[l][j]
    float M[8][8];
#pragma unroll
    for (int r = 0; r < 8; ++r) {
        const float4* xp = reinterpret_cast<const float4*>(x + base + r*512);
        const float4* yp = reinterpret_cast<const float4*>(y + base + r*512);
        float4 a0 = xp[0], a1 = xp[1];
        float4 b0 = yp[0], b1 = yp[1];
        float row[8] = {a0.x-b0.x, a0.y-b0.y, a0.z-b0.z, a0.w-b0.w,
                        a1.x-b1.x, a1.y-b1.y, a1.z-b1.z, a1.w-b1.w};
#pragma unroll
        for (int l = 0; l < 8; ++l) {
            float acc = row[0]*tT[l][0];
#pragma unroll
            for (int j = 1; j < 8; ++j) acc += row[j]*tT[l][j];
            M[r][l] = acc;
        }
    }

    // s = sum_{i,l} W[i][l] * (sum_r T[i][r]*M[r][l])^2
    float s = 0.0f;
#pragma unroll
    for (int i = 0; i < 8; ++i) {
        float4 w0 = reinterpret_cast<const float4*>(Wm)[2*i];
        float4 w1 = reinterpret_cast<const float4*>(Wm)[2*i+1];
        float wr[8] = {w0.x,w0.y,w0.z,w0.w,w1.x,w1.y,w1.z,w1.w};
#pragma unroll
        for (int l = 0; l < 8; ++l) {
            float d = tT[i][0]*M[0][l];
#pragma unroll
            for (int r = 1; r < 8; ++r) d += tT[i][r]*M[r][l];
            s += wr[l]*d*d;
        }
    }

    // deterministic workgroup reduction: wave shuffle + LDS across 4 waves
#pragma unroll
    for (int off = 32; off > 0; off >>= 1) s += __shfl_down(s, off, 64);
    __shared__ float wsum[WG/64];
    if ((tid & 63) == 0) wsum[tid >> 6] = s;
    __syncthreads();
    if (tid == 0) {
        float t = wsum[0];
#pragma unroll
        for (int w = 1; w < WG/64; ++w) t += wsum[w];
        ws[blockIdx.x] = t;
    }
}

__global__ __launch_bounds__(256) void spectral_reduce(
    const float* __restrict__ ws, float* __restrict__ out)
{
    const int tid = threadIdx.x;
    float s = ws[tid] + ws[tid + 256] + ws[tid + 512];
#pragma unroll
    for (int off = 32; off > 0; off >>= 1) s += __shfl_down(s, off, 64);
    __shared__ float wsum[4];
    if ((tid & 63) == 0) wsum[tid >> 6] = s;
    __syncthreads();
    if (tid == 0) out[0] = (wsum[0]+wsum[1]+wsum[2]+wsum[3]) * INV_N;
}

extern "C" void kernel_launch(void* const* d_in, const int* in_sizes, int n_in,
                              void* d_out, int out_size, void* d_ws, size_t ws_size,
                              hipStream_t stream) {
    const float* x  = (const float*)d_in[0];   // input  (16,3,512,512) f32
    const float* y  = (const float*)d_in[1];   // target (16,3,512,512) f32
    const float* Tm = (const float*)d_in[2];   // 8x8 DCT
    const float* Wm = (const float*)d_in[3];   // 8x8 weight
    float* ws  = (float*)d_ws;                 // 768 floats of partials
    float* out = (float*)d_out;                // scalar f32

    spectral_partial<<<NWG, WG, 0, stream>>>(x, y, Tm, Wm, ws);
    spectral_reduce<<<1, 256, 0, stream>>>(ws, out);
}